// Round 4
// baseline (267.942 us; speedup 1.0000x reference)
//
#include <hip/hip_runtime.h>
#include <math.h>

#define BB 32
#define CC 256
#define HH 64
#define WW 64
#define HWSZ (HH * WW)   // 4096
#define NCHUNK 16        // hw chunks per image (256 positions = 4 rows each)

typedef float f32x4 __attribute__((ext_vector_type(4)));

// ---------------------------------------------------------------------------
// Kernel 1: one pass over x. Grid: 32 b x 16 hw-chunks = 512 blocks, 256 thr.
// Wave w owns channels [64w, 64w+64); lane l owns float4 at hw0+4l.
// (R1-measured form: 8 KB LDS, butterfly channel reduce — HBM-bound, the
// 384 ds_swizzles/wave are ~4% of the wave's memory cycles.)
// ---------------------------------------------------------------------------
__global__ __launch_bounds__(256, 2) void stats_kernel(
    const float* __restrict__ x, float* __restrict__ chan_part,
    float* __restrict__ pool_max, float* __restrict__ pool_sum) {
  const int b = blockIdx.x >> 4;
  const int chunk = blockIdx.x & 15;
  const int hw0 = chunk << 8;
  const int tid = threadIdx.x;
  const int wave = tid >> 6;
  const int lane = tid & 63;
  const int c_base = wave << 6;

  const float4* xp =
      (const float4*)(x + ((size_t)b << 20) + ((size_t)c_base << 12) + hw0) + lane;

  float4 mx = make_float4(-3.4e38f, -3.4e38f, -3.4e38f, -3.4e38f);
  float4 sm = make_float4(0.f, 0.f, 0.f, 0.f);

  for (int g = 0; g < 4; ++g) {
    float s[16];
#pragma unroll
    for (int ci = 0; ci < 16; ++ci) {
      const float4 v = xp[(g * 16 + ci) * (HWSZ / 4)];
      mx.x = fmaxf(mx.x, v.x); mx.y = fmaxf(mx.y, v.y);
      mx.z = fmaxf(mx.z, v.z); mx.w = fmaxf(mx.w, v.w);
      sm.x += v.x; sm.y += v.y; sm.z += v.z; sm.w += v.w;
      s[ci] = (v.x + v.y) + (v.z + v.w);
    }
#pragma unroll
    for (int ci = 0; ci < 16; ++ci) {
      float v = s[ci];
#pragma unroll
      for (int off = 32; off > 0; off >>= 1) v += __shfl_xor(v, off, 64);
      s[ci] = v;
    }
    if (lane == 0) {
      float4* cp = (float4*)(chan_part +
                             ((size_t)(b * NCHUNK + chunk)) * CC + c_base + g * 16);
      cp[0] = make_float4(s[0],  s[1],  s[2],  s[3]);
      cp[1] = make_float4(s[4],  s[5],  s[6],  s[7]);
      cp[2] = make_float4(s[8],  s[9],  s[10], s[11]);
      cp[3] = make_float4(s[12], s[13], s[14], s[15]);
    }
  }

  __shared__ float4 lmax[4][64];
  __shared__ float4 lsum[4][64];
  lmax[wave][lane] = mx;
  lsum[wave][lane] = sm;
  __syncthreads();
  if (tid < 64) {
    const float4 a = lmax[0][tid], b4 = lmax[1][tid];
    const float4 c4 = lmax[2][tid], d4 = lmax[3][tid];
    float4 M;
    M.x = fmaxf(fmaxf(a.x, b4.x), fmaxf(c4.x, d4.x));
    M.y = fmaxf(fmaxf(a.y, b4.y), fmaxf(c4.y, d4.y));
    M.z = fmaxf(fmaxf(a.z, b4.z), fmaxf(c4.z, d4.z));
    M.w = fmaxf(fmaxf(a.w, b4.w), fmaxf(c4.w, d4.w));
    const float4 sa = lsum[0][tid], sb = lsum[1][tid];
    const float4 sc = lsum[2][tid], sd = lsum[3][tid];
    float4 S;
    S.x = (sa.x + sb.x) + (sc.x + sd.x);
    S.y = (sa.y + sb.y) + (sc.y + sd.y);
    S.z = (sa.z + sb.z) + (sc.z + sd.z);
    S.w = (sa.w + sb.w) + (sc.w + sd.w);
    ((float4*)(pool_max + ((size_t)b << 12) + hw0))[tid] = M;
    ((float4*)(pool_sum + ((size_t)b << 12) + hw0))[tid] = S;
  }
}

// ---------------------------------------------------------------------------
// Kernel 2 (fully fused): per (b, 256-position chunk) block:
//   prologue A: ch_w for all 256 channels (fold chunk partials, conv1d k=5,
//               sigmoid, +1) -> LDS  (16x redundant per b; trivial)
//   prologue B: sp for the chunk's 4x64 positions via 7x7 conv over a
//               zero-padded 10x72 LDS tile of pool_max/pool_sum
//   main: stream x -> out = x * (ch_w[c] + sp[hw]); nontemporal stores.
// Removes the separate attention dispatch and the sp/ch_w global round-trip.
// ---------------------------------------------------------------------------
__global__ __launch_bounds__(256) void fused_kernel(
    const float* __restrict__ x, const float* __restrict__ chan_part,
    const float* __restrict__ pool_max, const float* __restrict__ pool_sum,
    const float* __restrict__ w5, const float* __restrict__ w2,
    const float* __restrict__ bias, float* __restrict__ out) {
  const int b = blockIdx.x >> 4;
  const int chunk = blockIdx.x & 15;
  const int hw0 = chunk << 8;
  const int r0 = chunk << 2;            // first row of this chunk
  const int tid = threadIdx.x;
  const int wave = tid >> 6;
  const int lane4 = tid & 63;

  __shared__ float m[CC];               // channel means
  __shared__ float chw_s[CC];           // 1 + sigmoid(conv1d(m))
  __shared__ float tmax[10][72];        // zero-padded pool tiles
  __shared__ float tsum[10][72];
  __shared__ float sp_s[256];           // sigmoid(conv2d) per position

  // ---- prologue A.1: channel means ----
  {
    float s = 0.0f;
#pragma unroll
    for (int k = 0; k < NCHUNK; ++k)
      s += chan_part[(size_t)(b * NCHUNK + k) * CC + tid];
    m[tid] = s * (1.0f / HWSZ);
  }

  // ---- prologue B.1: pool tile with zero halo ----
  for (int idx = tid; idx < 720; idx += 256) {
    const int row = idx / 72;
    const int col = idx - row * 72;
    const int hh = r0 - 3 + row;
    const int wcol = col - 3;
    float vm = 0.0f, vs = 0.0f;
    if (hh >= 0 && hh < HH && wcol >= 0 && wcol < WW) {
      const int off = (b << 12) + (hh << 6) + wcol;
      vm = pool_max[off];
      vs = pool_sum[off];
    }
    tmax[row][col] = vm;
    tsum[row][col] = vs;
  }
  __syncthreads();

  // ---- prologue A.2: conv1d(k=5) + sigmoid + 1 ----
  {
    float acc = 0.0f;
#pragma unroll
    for (int k = 0; k < 5; ++k) {
      const int cc = tid + k - 2;
      const float v = (cc >= 0 && cc < CC) ? m[cc] : 0.0f;
      acc = fmaf(v, w5[k], acc);
    }
    chw_s[tid] = 1.0f + 1.0f / (1.0f + __expf(-acc));
  }

  // ---- prologue B.2: 7x7 conv + bias + sigmoid over this chunk ----
  {
    const int lr = tid >> 6;            // 0..3 local row
    const int w = tid & 63;             // col
    float acc = bias[0];
#pragma unroll
    for (int kh = 0; kh < 7; ++kh) {
#pragma unroll
      for (int kw = 0; kw < 7; ++kw) {
        acc = fmaf(tmax[lr + kh][w + kw], w2[kh * 7 + kw], acc);
        acc = fmaf(tsum[lr + kh][w + kw], w2[49 + kh * 7 + kw] * (1.0f / CC), acc);
      }
    }
    sp_s[tid] = 1.0f / (1.0f + __expf(-acc));
  }
  __syncthreads();

  // ---- main: stream all 256 channels of this chunk ----
  const float4* xb = (const float4*)(x + ((size_t)b << 20) + hw0);
  f32x4* ob = (f32x4*)(out + ((size_t)b << 20) + hw0);
  const float4 sp4 = ((const float4*)sp_s)[lane4];   // constant per thread

#pragma unroll 4
  for (int cg = 0; cg < 64; ++cg) {
    const int c = (cg << 2) + wave;                  // wave-uniform channel
    const float cw = chw_s[c];                       // includes +1
    const float4 x4 = xb[(c << 10) + lane4];
    f32x4 o;
    o.x = x4.x * (cw + sp4.x);
    o.y = x4.y * (cw + sp4.y);
    o.z = x4.z * (cw + sp4.z);
    o.w = x4.w * (cw + sp4.w);
    __builtin_nontemporal_store(o, ob + (c << 10) + lane4);
  }
}

extern "C" void kernel_launch(void* const* d_in, const int* in_sizes, int n_in,
                              void* d_out, int out_size, void* d_ws, size_t ws_size,
                              hipStream_t stream) {
  const float* x    = (const float*)d_in[0];  // (32,256,64,64)
  const float* w1   = (const float*)d_in[1];  // (1,1,5)
  const float* w2   = (const float*)d_in[2];  // (1,2,7,7)
  const float* bias = (const float*)d_in[3];  // (1,)
  float* out = (float*)d_out;

  float* ws = (float*)d_ws;
  float* chan_part = ws;                       // 32*16*256 = 131072 floats
  float* pool_max  = ws + 131072;              // 131072
  float* pool_sum  = ws + 262144;              // 131072
  // Every workspace word is fully written before it is read -> no memsets,
  // no atomics, no init-pattern dependence.

  stats_kernel<<<BB * NCHUNK, 256, 0, stream>>>(x, chan_part, pool_max, pool_sum);
  fused_kernel<<<BB * NCHUNK, 256, 0, stream>>>(
      x, chan_part, pool_max, pool_sum, w1, w2, bias, out);
}

// Round 5
// 259.678 us; speedup vs baseline: 1.0318x; 1.0318x over previous
//
#include <hip/hip_runtime.h>
#include <math.h>

#define BB 32
#define CC 256
#define HH 64
#define WW 64
#define HWSZ (HH * WW)   // 4096
#define NCHUNK 16        // hw chunks per image (256 positions = 4 rows each)

typedef float f32x4 __attribute__((ext_vector_type(4)));

// ---------------------------------------------------------------------------
// Kernel 1: one pass over x.
// Grid: 32 b x 16 hw-chunks x 2 channel-halves = 1024 blocks (4 blocks/CU,
// 16 waves/CU -- double R1's residency; stats was the latency-limited one).
// Wave w owns 32 channels [half*128 + 32w, +32) over the chunk's 256
// positions (lane l -> float4 at hw0+4l).
// Pool partials per half go to separate buffers -> still ZERO atomics;
// attn merges the two halves on read (trivial).
// ---------------------------------------------------------------------------
__global__ __launch_bounds__(256) void stats_kernel(
    const float* __restrict__ x, float* __restrict__ chan_part,
    float* __restrict__ pmax0, float* __restrict__ psum0,
    float* __restrict__ pmax1, float* __restrict__ psum1) {
  const int b = blockIdx.x >> 5;
  const int rem = blockIdx.x & 31;
  const int chunk = rem >> 1;
  const int half = rem & 1;
  const int hw0 = chunk << 8;
  const int tid = threadIdx.x;
  const int wave = tid >> 6;
  const int lane = tid & 63;
  const int c_base = (half << 7) + (wave << 5);   // 32 channels per wave

  const float4* xp =
      (const float4*)(x + ((size_t)b << 20) + ((size_t)c_base << 12) + hw0) + lane;

  float4 mx = make_float4(-3.4e38f, -3.4e38f, -3.4e38f, -3.4e38f);
  float4 sm = make_float4(0.f, 0.f, 0.f, 0.f);

  for (int g = 0; g < 2; ++g) {
    float s[16];
#pragma unroll
    for (int ci = 0; ci < 16; ++ci) {
      const float4 v = xp[(g * 16 + ci) * (HWSZ / 4)];
      mx.x = fmaxf(mx.x, v.x); mx.y = fmaxf(mx.y, v.y);
      mx.z = fmaxf(mx.z, v.z); mx.w = fmaxf(mx.w, v.w);
      sm.x += v.x; sm.y += v.y; sm.z += v.z; sm.w += v.w;
      s[ci] = (v.x + v.y) + (v.z + v.w);
    }
#pragma unroll
    for (int ci = 0; ci < 16; ++ci) {
      float v = s[ci];
#pragma unroll
      for (int off = 32; off > 0; off >>= 1) v += __shfl_xor(v, off, 64);
      s[ci] = v;
    }
    if (lane == 0) {
      float4* cp = (float4*)(chan_part +
                             ((size_t)(b * NCHUNK + chunk)) * CC + c_base + g * 16);
      cp[0] = make_float4(s[0],  s[1],  s[2],  s[3]);
      cp[1] = make_float4(s[4],  s[5],  s[6],  s[7]);
      cp[2] = make_float4(s[8],  s[9],  s[10], s[11]);
      cp[3] = make_float4(s[12], s[13], s[14], s[15]);
    }
  }

  __shared__ float4 lmax[4][64];
  __shared__ float4 lsum[4][64];
  lmax[wave][lane] = mx;
  lsum[wave][lane] = sm;
  __syncthreads();
  if (tid < 64) {
    const float4 a = lmax[0][tid], b4 = lmax[1][tid];
    const float4 c4 = lmax[2][tid], d4 = lmax[3][tid];
    float4 M;
    M.x = fmaxf(fmaxf(a.x, b4.x), fmaxf(c4.x, d4.x));
    M.y = fmaxf(fmaxf(a.y, b4.y), fmaxf(c4.y, d4.y));
    M.z = fmaxf(fmaxf(a.z, b4.z), fmaxf(c4.z, d4.z));
    M.w = fmaxf(fmaxf(a.w, b4.w), fmaxf(c4.w, d4.w));
    const float4 sa = lsum[0][tid], sb = lsum[1][tid];
    const float4 sc = lsum[2][tid], sd = lsum[3][tid];
    float4 S;
    S.x = (sa.x + sb.x) + (sc.x + sd.x);
    S.y = (sa.y + sb.y) + (sc.y + sd.y);
    S.z = (sa.z + sb.z) + (sc.z + sd.z);
    S.w = (sa.w + sb.w) + (sc.w + sd.w);
    float* pm = half ? pmax1 : pmax0;
    float* ps = half ? psum1 : psum0;
    ((float4*)(pm + ((size_t)b << 12) + hw0))[tid] = M;
    ((float4*)(ps + ((size_t)b << 12) + hw0))[tid] = S;
  }
}

// ---------------------------------------------------------------------------
// Kernel 2: blocks [0,32) = ECA (fold chunk partials, conv1d k=5, sigmoid);
// blocks [32,544) = spatial 7x7 conv + sigmoid over an LDS tile built by
// merging the two pool halves (max / add).
// ---------------------------------------------------------------------------
__global__ __launch_bounds__(256) void attn_kernel(
    const float* __restrict__ chan_part, const float* __restrict__ w5,
    float* __restrict__ ch_w,
    const float* __restrict__ pmax0, const float* __restrict__ psum0,
    const float* __restrict__ pmax1, const float* __restrict__ psum1,
    const float* __restrict__ w2, const float* __restrict__ bias,
    float* __restrict__ sp) {
  if (blockIdx.x < BB) {
    __shared__ float m[CC];
    const int b = blockIdx.x;
    const int c = threadIdx.x;
    float s = 0.0f;
#pragma unroll
    for (int k = 0; k < NCHUNK; ++k)
      s += chan_part[(size_t)(b * NCHUNK + k) * CC + c];
    m[c] = s * (1.0f / HWSZ);
    __syncthreads();

    float acc = 0.0f;
#pragma unroll
    for (int k = 0; k < 5; ++k) {
      int cc = c + k - 2;
      float v = (cc >= 0 && cc < CC) ? m[cc] : 0.0f;
      acc = fmaf(v, w5[k], acc);
    }
    ch_w[b * CC + c] = 1.0f / (1.0f + __expf(-acc));
  } else {
    const int sblk = blockIdx.x - BB;     // 512 spatial blocks
    const int b = sblk >> 4;
    const int chunk = sblk & 15;
    const int r0 = chunk << 2;
    const int tid = threadIdx.x;

    __shared__ float tmax[10][72];
    __shared__ float tsum[10][72];
    for (int idx = tid; idx < 720; idx += 256) {
      const int row = idx / 72;
      const int col = idx - row * 72;
      const int hh = r0 - 3 + row;
      const int wcol = col - 3;
      float vm = 0.0f, vs = 0.0f;
      if (hh >= 0 && hh < HH && wcol >= 0 && wcol < WW) {
        const int off = (b << 12) + (hh << 6) + wcol;
        vm = fmaxf(pmax0[off], pmax1[off]);
        vs = psum0[off] + psum1[off];
      }
      tmax[row][col] = vm;
      tsum[row][col] = vs;
    }
    __syncthreads();

    const int lr = tid >> 6;
    const int w = tid & 63;
    float acc = bias[0];
#pragma unroll
    for (int kh = 0; kh < 7; ++kh) {
#pragma unroll
      for (int kw = 0; kw < 7; ++kw) {
        acc = fmaf(tmax[lr + kh][w + kw], w2[kh * 7 + kw], acc);
        acc = fmaf(tsum[lr + kh][w + kw], w2[49 + kh * 7 + kw] * (1.0f / CC), acc);
      }
    }
    sp[(b << 12) + (chunk << 8) + tid] = 1.0f / (1.0f + __expf(-acc));
  }
}

// ---------------------------------------------------------------------------
// Kernel 3: out = x * (ch_w[b,c] + sp[b,hw] + 1). Block-uniform (b,c) ->
// scalar ch_w; nontemporal float4 stores. 32768 blocks, pure streaming.
// ---------------------------------------------------------------------------
__global__ __launch_bounds__(256) void combine_kernel(
    const float* __restrict__ x, const float* __restrict__ ch_w,
    const float* __restrict__ sp, float* __restrict__ out) {
  const int blk = blockIdx.x;            // 32768 blocks; 1024 elems each
  const int b = blk >> 10;
  const int c = (blk >> 2) & 255;
  const int hw0 = (blk & 3) << 10;
  const int t4 = threadIdx.x;

  const float cw = 1.0f + ch_w[b * CC + c];
  const size_t plane = ((size_t)b << 20) + ((size_t)c << 12) + hw0;
  const float4 x4 = ((const float4*)(x + plane))[t4];
  const float4 s4 = ((const float4*)(sp + ((size_t)b << 12) + hw0))[t4];

  f32x4 o;
  o.x = x4.x * (cw + s4.x);
  o.y = x4.y * (cw + s4.y);
  o.z = x4.z * (cw + s4.z);
  o.w = x4.w * (cw + s4.w);
  __builtin_nontemporal_store(o, (f32x4*)(out + plane) + t4);
}

extern "C" void kernel_launch(void* const* d_in, const int* in_sizes, int n_in,
                              void* d_out, int out_size, void* d_ws, size_t ws_size,
                              hipStream_t stream) {
  const float* x    = (const float*)d_in[0];  // (32,256,64,64)
  const float* w1   = (const float*)d_in[1];  // (1,1,5)
  const float* w2   = (const float*)d_in[2];  // (1,2,7,7)
  const float* bias = (const float*)d_in[3];  // (1,)
  float* out = (float*)d_out;

  float* ws = (float*)d_ws;
  float* chan_part = ws;                       // 131072 floats
  float* ch_w      = ws + 131072;              // 8192
  float* pmax0     = ws + 139264;              // 131072
  float* psum0     = ws + 270336;              // 131072
  float* pmax1     = ws + 401408;              // 131072
  float* psum1     = ws + 532480;              // 131072
  float* sp        = ws + 663552;              // 131072
  // Every workspace word is written before it is read -> no memsets,
  // no atomics, no init-pattern dependence.

  stats_kernel<<<BB * NCHUNK * 2, 256, 0, stream>>>(
      x, chan_part, pmax0, psum0, pmax1, psum1);
  attn_kernel<<<BB + BB * NCHUNK, 256, 0, stream>>>(
      chan_part, w1, ch_w, pmax0, psum0, pmax1, psum1, w2, bias, sp);
  combine_kernel<<<(BB * CC * HWSZ) / (4 * 256), 256, 0, stream>>>(x, ch_w, sp, out);
}

// Round 6
// 257.987 us; speedup vs baseline: 1.0386x; 1.0066x over previous
//
#include <hip/hip_runtime.h>
#include <math.h>

#define BB 32
#define CC 256
#define HH 64
#define WW 64
#define HWSZ (HH * WW)   // 4096

typedef float f32x4 __attribute__((ext_vector_type(4)));

// ---------------------------------------------------------------------------
// Kernel 1: one pass over x.
// Grid: 32 b x 4 position-quarters (1024 pos) x 4 channel-quarters = 512
// blocks, 256 thr. Wave w owns 16 channels [cq*64+16w, +16) over the
// quarter's 1024 positions.
//
// Key change vs R1-R5: each channel is read as FOUR CONSECUTIVE 1 KiB loads
// (4 KiB contiguous run) instead of a single 1 KiB load strided 16 KiB from
// the next. Same bytes, 4x longer DRAM runs — stats has been access-pattern
// bound (R0: 1.65 TB/s effective with half the fetches already L3 hits).
// Also 4x fewer butterfly reductions (16/wave, one per channel).
// Pool partials per channel-quarter go to 4 separate buffers -> no atomics;
// attn merges the 4 on read.
// ---------------------------------------------------------------------------
__global__ __launch_bounds__(256) void stats_kernel(
    const float* __restrict__ x, float* __restrict__ chan_part,
    float* __restrict__ pmax, float* __restrict__ psum) {
  const int b = blockIdx.x >> 4;
  const int q = (blockIdx.x >> 2) & 3;   // position quarter (1024 positions)
  const int cq = blockIdx.x & 3;         // channel quarter (64 channels)
  const int tid = threadIdx.x;
  const int wave = tid >> 6;
  const int lane = tid & 63;
  const int c0 = (cq << 6) + (wave << 4);  // first channel of this wave

  __shared__ float4 lmax[4][4][64];   // [wave][g][lane]
  __shared__ float4 lsum[4][4][64];

  float4 mx[4], sm[4];
#pragma unroll
  for (int g = 0; g < 4; ++g) {
    mx[g] = make_float4(-3.4e38f, -3.4e38f, -3.4e38f, -3.4e38f);
    sm[g] = make_float4(0.f, 0.f, 0.f, 0.f);
  }
  float own = 0.0f;   // lane ci ends up holding channel c0+ci's sum

  // float4 base: channel stride = 1024 float4s; g stride = 64 float4s.
  const float4* xb =
      (const float4*)(x + ((size_t)b << 20) + ((size_t)c0 << 12) + (q << 10)) + lane;

#pragma unroll 2
  for (int ci = 0; ci < 16; ++ci) {
    const float4* xc = xb + ci * (HWSZ / 4);
    const float4 v0 = xc[0];
    const float4 v1 = xc[64];
    const float4 v2 = xc[128];
    const float4 v3 = xc[192];

    mx[0].x = fmaxf(mx[0].x, v0.x); mx[0].y = fmaxf(mx[0].y, v0.y);
    mx[0].z = fmaxf(mx[0].z, v0.z); mx[0].w = fmaxf(mx[0].w, v0.w);
    mx[1].x = fmaxf(mx[1].x, v1.x); mx[1].y = fmaxf(mx[1].y, v1.y);
    mx[1].z = fmaxf(mx[1].z, v1.z); mx[1].w = fmaxf(mx[1].w, v1.w);
    mx[2].x = fmaxf(mx[2].x, v2.x); mx[2].y = fmaxf(mx[2].y, v2.y);
    mx[2].z = fmaxf(mx[2].z, v2.z); mx[2].w = fmaxf(mx[2].w, v2.w);
    mx[3].x = fmaxf(mx[3].x, v3.x); mx[3].y = fmaxf(mx[3].y, v3.y);
    mx[3].z = fmaxf(mx[3].z, v3.z); mx[3].w = fmaxf(mx[3].w, v3.w);

    sm[0].x += v0.x; sm[0].y += v0.y; sm[0].z += v0.z; sm[0].w += v0.w;
    sm[1].x += v1.x; sm[1].y += v1.y; sm[1].z += v1.z; sm[1].w += v1.w;
    sm[2].x += v2.x; sm[2].y += v2.y; sm[2].z += v2.z; sm[2].w += v2.w;
    sm[3].x += v3.x; sm[3].y += v3.y; sm[3].z += v3.z; sm[3].w += v3.w;

    float s = ((v0.x + v0.y) + (v0.z + v0.w)) + ((v1.x + v1.y) + (v1.z + v1.w)) +
              ((v2.x + v2.y) + (v2.z + v2.w)) + ((v3.x + v3.y) + (v3.z + v3.w));
#pragma unroll
    for (int off = 32; off > 0; off >>= 1) s += __shfl_xor(s, off, 64);
    if (lane == ci) own = s;
  }

  if (lane < 16)
    chan_part[(size_t)((b << 2) + q) * CC + c0 + lane] = own;

#pragma unroll
  for (int g = 0; g < 4; ++g) {
    lmax[wave][g][lane] = mx[g];
    lsum[wave][g][lane] = sm[g];
  }
  __syncthreads();

  // 256 threads merge the 4 waves' (disjoint-channel) partials; one float4
  // position each: position = q*1024 + g*256 + l*4.
  {
    const int g = tid >> 6;
    const int l = tid & 63;
    const float4 a = lmax[0][g][l], b4 = lmax[1][g][l];
    const float4 c4 = lmax[2][g][l], d4 = lmax[3][g][l];
    float4 M;
    M.x = fmaxf(fmaxf(a.x, b4.x), fmaxf(c4.x, d4.x));
    M.y = fmaxf(fmaxf(a.y, b4.y), fmaxf(c4.y, d4.y));
    M.z = fmaxf(fmaxf(a.z, b4.z), fmaxf(c4.z, d4.z));
    M.w = fmaxf(fmaxf(a.w, b4.w), fmaxf(c4.w, d4.w));
    const float4 sa = lsum[0][g][l], sb = lsum[1][g][l];
    const float4 sc = lsum[2][g][l], sd = lsum[3][g][l];
    float4 S;
    S.x = (sa.x + sb.x) + (sc.x + sd.x);
    S.y = (sa.y + sb.y) + (sc.y + sd.y);
    S.z = (sa.z + sb.z) + (sc.z + sd.z);
    S.w = (sa.w + sb.w) + (sc.w + sd.w);
    // pmax/psum layout: [cq][b][HWSZ]; float4 index:
    const int f4 = ((cq * BB + b) << 10) + (q << 8) + (g << 6) + l;
    ((float4*)pmax)[f4] = M;
    ((float4*)psum)[f4] = S;
  }
}

// ---------------------------------------------------------------------------
// Kernel 2: blocks [0,32) = ECA (fold 4 q-partials, conv1d k=5, sigmoid);
// blocks [32,544) = spatial 7x7 conv + sigmoid over an LDS tile built by
// merging the four channel-quarter pool buffers (max / add).
// ---------------------------------------------------------------------------
__global__ __launch_bounds__(256) void attn_kernel(
    const float* __restrict__ chan_part, const float* __restrict__ w5,
    float* __restrict__ ch_w,
    const float* __restrict__ pmax, const float* __restrict__ psum,
    const float* __restrict__ w2, const float* __restrict__ bias,
    float* __restrict__ sp) {
  if (blockIdx.x < BB) {
    __shared__ float m[CC];
    const int b = blockIdx.x;
    const int c = threadIdx.x;
    float s = 0.0f;
#pragma unroll
    for (int k = 0; k < 4; ++k)
      s += chan_part[(size_t)((b << 2) + k) * CC + c];
    m[c] = s * (1.0f / HWSZ);
    __syncthreads();

    float acc = 0.0f;
#pragma unroll
    for (int k = 0; k < 5; ++k) {
      int cc = c + k - 2;
      float v = (cc >= 0 && cc < CC) ? m[cc] : 0.0f;
      acc = fmaf(v, w5[k], acc);
    }
    ch_w[b * CC + c] = 1.0f / (1.0f + __expf(-acc));
  } else {
    const int sblk = blockIdx.x - BB;     // 512 spatial blocks (4 rows each)
    const int b = sblk >> 4;
    const int chunk = sblk & 15;
    const int r0 = chunk << 2;
    const int tid = threadIdx.x;

    __shared__ float tmax[10][72];
    __shared__ float tsum[10][72];
    for (int idx = tid; idx < 720; idx += 256) {
      const int row = idx / 72;
      const int col = idx - row * 72;
      const int hh = r0 - 3 + row;
      const int wcol = col - 3;
      float vm = 0.0f, vs = 0.0f;
      if (hh >= 0 && hh < HH && wcol >= 0 && wcol < WW) {
        const int off = (b << 12) + (hh << 6) + wcol;
        const float m0 = pmax[off], m1 = pmax[(BB << 12) + off];
        const float m2 = pmax[(2 * BB << 12) + off], m3 = pmax[(3 * BB << 12) + off];
        vm = fmaxf(fmaxf(m0, m1), fmaxf(m2, m3));
        vs = (psum[off] + psum[(BB << 12) + off]) +
             (psum[(2 * BB << 12) + off] + psum[(3 * BB << 12) + off]);
      }
      tmax[row][col] = vm;
      tsum[row][col] = vs;
    }
    __syncthreads();

    const int lr = tid >> 6;
    const int w = tid & 63;
    float acc = bias[0];
#pragma unroll
    for (int kh = 0; kh < 7; ++kh) {
#pragma unroll
      for (int kw = 0; kw < 7; ++kw) {
        acc = fmaf(tmax[lr + kh][w + kw], w2[kh * 7 + kw], acc);
        acc = fmaf(tsum[lr + kh][w + kw], w2[49 + kh * 7 + kw] * (1.0f / CC), acc);
      }
    }
    sp[(b << 12) + (chunk << 8) + tid] = 1.0f / (1.0f + __expf(-acc));
  }
}

// ---------------------------------------------------------------------------
// Kernel 3: out = x * (ch_w[b,c] + sp[b,hw] + 1). Block-uniform (b,c) ->
// scalar ch_w; nontemporal float4 stores. 32768 blocks, pure streaming.
// ---------------------------------------------------------------------------
__global__ __launch_bounds__(256) void combine_kernel(
    const float* __restrict__ x, const float* __restrict__ ch_w,
    const float* __restrict__ sp, float* __restrict__ out) {
  const int blk = blockIdx.x;            // 32768 blocks; 1024 elems each
  const int b = blk >> 10;
  const int c = (blk >> 2) & 255;
  const int hw0 = (blk & 3) << 10;
  const int t4 = threadIdx.x;

  const float cw = 1.0f + ch_w[b * CC + c];
  const size_t plane = ((size_t)b << 20) + ((size_t)c << 12) + hw0;
  const float4 x4 = ((const float4*)(x + plane))[t4];
  const float4 s4 = ((const float4*)(sp + ((size_t)b << 12) + hw0))[t4];

  f32x4 o;
  o.x = x4.x * (cw + s4.x);
  o.y = x4.y * (cw + s4.y);
  o.z = x4.z * (cw + s4.z);
  o.w = x4.w * (cw + s4.w);
  __builtin_nontemporal_store(o, (f32x4*)(out + plane) + t4);
}

extern "C" void kernel_launch(void* const* d_in, const int* in_sizes, int n_in,
                              void* d_out, int out_size, void* d_ws, size_t ws_size,
                              hipStream_t stream) {
  const float* x    = (const float*)d_in[0];  // (32,256,64,64)
  const float* w1   = (const float*)d_in[1];  // (1,1,5)
  const float* w2   = (const float*)d_in[2];  // (1,2,7,7)
  const float* bias = (const float*)d_in[3];  // (1,)
  float* out = (float*)d_out;

  float* ws = (float*)d_ws;
  float* chan_part = ws;                       // 32*4*256  = 32768 floats
  float* ch_w      = ws + 32768;               // 8192
  float* pmax      = ws + 40960;               // 4*131072 = 524288
  float* psum      = ws + 565248;              // 524288
  float* sp        = ws + 1089536;             // 131072
  // Every workspace word is written before it is read -> no memsets,
  // no atomics, no init-pattern dependence.

  stats_kernel<<<BB * 16, 256, 0, stream>>>(x, chan_part, pmax, psum);
  attn_kernel<<<BB + BB * 16, 256, 0, stream>>>(
      chan_part, w1, ch_w, pmax, psum, w2, bias, sp);
  combine_kernel<<<(BB * CC * HWSZ) / (4 * 256), 256, 0, stream>>>(x, ch_w, sp, out);
}